// Round 1
// baseline (99.868 us; speedup 1.0000x reference)
//
#include <hip/hip_runtime.h>
#include <math.h>

#define SEQ 2048
#define NB 4
#define THREADS 256
#define K1_BLOCKS 1024            // 4 batches * 256 blocks
#define ROWS_PER_K1 8             // 2048 / 256

__device__ __forceinline__ float wave_reduce_add_f(float v) {
    #pragma unroll
    for (int o = 32; o > 0; o >>= 1) v += __shfl_down(v, o, 64);
    return v;
}
__device__ __forceinline__ double wave_reduce_add_d(double v) {
    #pragma unroll
    for (int o = 32; o > 0; o >>= 1) v += __shfl_down(v, o, 64);
    return v;
}

// Pass 1: per-block partial (sum, sumsq) of dist_sq, in double.
__global__ __launch_bounds__(THREADS) void k_stats(const float* __restrict__ r,
                                                   double* __restrict__ partials) {
    const int bid  = blockIdx.x;        // 0..1023
    const int b    = bid >> 8;          // batch
    const int rblk = bid & 255;
    const float* rp = r + (size_t)b * SEQ * 4;
    __shared__ float4 u[SEQ];           // (1 - r_t), 32KB
    const int tid = threadIdx.x;

    #pragma unroll
    for (int j = 0; j < 8; ++j) {
        float4 v = ((const float4*)rp)[tid + THREADS * j];
        float4 w; w.x = 1.f - v.x; w.y = 1.f - v.y; w.z = 1.f - v.z; w.w = 1.f - v.w;
        u[tid + THREADS * j] = w;
    }
    __syncthreads();

    double sum = 0.0, sumsq = 0.0;
    for (int rr = 0; rr < ROWS_PER_K1; ++rr) {
        const int s = rblk * ROWS_PER_K1 + rr;
        const float rs0 = rp[4*s+0], rs1 = rp[4*s+1], rs2 = rp[4*s+2], rs3 = rp[4*s+3];
        #pragma unroll
        for (int j = 0; j < 8; ++j) {
            float4 w = u[tid + THREADS * j];
            float d0 = rs0 * w.x, d1 = rs1 * w.y, d2 = rs2 * w.z, d3 = rs3 * w.w;
            float s01  = d0*d0 + d1*d1;
            float dist = (s01 + d2*d2) + d3*d3;
            sum   += (double)dist;
            sumsq += (double)dist * (double)dist;
        }
    }

    sum   = wave_reduce_add_d(sum);
    sumsq = wave_reduce_add_d(sumsq);
    __shared__ double red[8];
    const int wid = tid >> 6, lane = tid & 63;
    if (lane == 0) { red[wid*2] = sum; red[wid*2+1] = sumsq; }
    __syncthreads();
    if (tid == 0) {
        partials[bid*2+0] = red[0] + red[2] + red[4] + red[6];
        partials[bid*2+1] = red[1] + red[3] + red[5] + red[7];
    }
}

// Pass 2: per-batch threshold = mean + 1.25 * std(ddof=1), std clipped at 1e-6.
__global__ __launch_bounds__(THREADS) void k_thresh(const double* __restrict__ partials,
                                                    float* __restrict__ thr) {
    const int b = blockIdx.x;
    const int tid = threadIdx.x;
    double s = partials[(b*256 + tid)*2 + 0];
    double q = partials[(b*256 + tid)*2 + 1];
    s = wave_reduce_add_d(s);
    q = wave_reduce_add_d(q);
    __shared__ double red[8];
    const int wid = tid >> 6, lane = tid & 63;
    if (lane == 0) { red[wid*2] = s; red[wid*2+1] = q; }
    __syncthreads();
    if (tid == 0) {
        double S0 = red[0] + red[2] + red[4] + red[6];
        double S1 = red[1] + red[3] + red[5] + red[7];
        const double N = (double)SEQ * (double)SEQ;
        double mean = S0 / N;
        double var  = (S1 - S0 * S0 / N) / (N - 1.0);
        if (var < 0.0) var = 0.0;
        double sd = sqrt(var);
        if (sd < 1e-6) sd = 1e-6;
        thr[b] = (float)(mean + 1.25 * sd);
    }
}

// Pass 3: one block per output row. Compute bias, mask, row-normalize, write.
__global__ __launch_bounds__(THREADS) void k_attn(const float* __restrict__ r,
                                                  const float* __restrict__ thr,
                                                  float* __restrict__ out) {
    const int srow = blockIdx.x;   // 0..2047
    const int b    = blockIdx.y;   // 0..3
    const float* rp = r + (size_t)b * SEQ * 4;
    __shared__ float4 u[SEQ];      // 32KB; reused as the output repack buffer
    __shared__ float redf[4];
    const int tid = threadIdx.x;

    #pragma unroll
    for (int j = 0; j < 8; ++j) {
        float4 v = ((const float4*)rp)[tid + THREADS * j];
        float4 w; w.x = 1.f - v.x; w.y = 1.f - v.y; w.z = 1.f - v.z; w.w = 1.f - v.w;
        u[tid + THREADS * j] = w;
    }
    const float rs0 = rp[4*srow+0], rs1 = rp[4*srow+1];
    const float rs2 = rp[4*srow+2], rs3 = rp[4*srow+3];
    const float T = thr[b];
    __syncthreads();

    float att[8];
    float rowsum = 0.f;
    #pragma unroll
    for (int j = 0; j < 8; ++j) {
        float4 w = u[tid + THREADS * j];
        float d0 = rs0 * w.x, d1 = rs1 * w.y, d2 = rs2 * w.z, d3 = rs3 * w.w;
        float s01  = d0*d0 + d1*d1;
        float dist = (s01 + d2*d2) + d3*d3;
        // cos(atan2(d1,d0)) == d0 / sqrt(d0^2+d1^2); atan2(0,0)=0 -> cos=1
        float cosv = (s01 > 0.f) ? d0 * rsqrtf(s01) : 1.f;
        float bias = 0.5f * (1.f + cosv) * __expf(-dist);
        float a = (dist <= T) ? bias : 0.f;
        rowsum += a;
        att[j] = a;
    }

    float v = wave_reduce_add_f(rowsum);
    const int wid = tid >> 6, lane = tid & 63;
    if (lane == 0) redf[wid] = v;
    __syncthreads();                 // also guarantees all u reads are done
    const float denom = (redf[0] + redf[1] + redf[2] + redf[3]) + 1e-8f;
    const float inv = 1.0f / denom;

    float* attbuf = (float*)u;       // reuse LDS
    #pragma unroll
    for (int j = 0; j < 8; ++j) attbuf[tid + THREADS * j] = att[j] * inv;
    __syncthreads();

    float4* ob = (float4*)(out + ((size_t)b * SEQ + srow) * SEQ);
    const float4* ab = (const float4*)attbuf;
    ob[tid]           = ab[tid];
    ob[tid + THREADS] = ab[tid + THREADS];
}

extern "C" void kernel_launch(void* const* d_in, const int* in_sizes, int n_in,
                              void* d_out, int out_size, void* d_ws, size_t ws_size,
                              hipStream_t stream) {
    const float* r = (const float*)d_in[0];
    float* out = (float*)d_out;
    double* partials = (double*)d_ws;                                  // 1024*2 doubles = 16KB
    float* thr = (float*)((char*)d_ws + (size_t)K1_BLOCKS * 2 * sizeof(double)); // 4 floats

    k_stats <<<dim3(K1_BLOCKS), THREADS, 0, stream>>>(r, partials);
    k_thresh<<<dim3(NB),        THREADS, 0, stream>>>(partials, thr);
    k_attn  <<<dim3(SEQ, NB),   THREADS, 0, stream>>>(r, thr, out);
}

// Round 2
// 97.869 us; speedup vs baseline: 1.0204x; 1.0204x over previous
//
#include <hip/hip_runtime.h>
#include <math.h>

#define SEQ 2048
#define NB 4
#define THREADS 256
#define K1_BLOCKS 1024            // 4 batches * 256 blocks
#define ROWS_PER_BLK 8            // both kernels: 8 rows per block

__device__ __forceinline__ float wave_bcast_add_f(float v) {
    #pragma unroll
    for (int o = 1; o < 64; o <<= 1) v += __shfl_xor(v, o, 64);
    return v;   // all lanes hold the sum
}
__device__ __forceinline__ double wave_reduce_add_d(double v) {
    #pragma unroll
    for (int o = 32; o > 0; o >>= 1) v += __shfl_down(v, o, 64);
    return v;   // lane 0 holds the sum
}

// Pass 1: per-block partial (sum, sumsq) of dist_sq.
// Per-thread accumulation in f32 (64 terms, rel err ~1e-6 -> threshold shift
// ~1e-5, harmless: border bias ~ exp(-thr) ~ 1e-7), f64 only across threads.
__global__ __launch_bounds__(THREADS) void k_stats(const float* __restrict__ r,
                                                   double* __restrict__ partials) {
    const int bid  = blockIdx.x;        // 0..1023
    const int b    = bid >> 8;          // batch
    const int rblk = bid & 255;
    const float* rp = r + (size_t)b * SEQ * 4;
    __shared__ float4 u[SEQ];           // (1 - r_t), 32KB
    const int tid = threadIdx.x;

    #pragma unroll
    for (int j = 0; j < 8; ++j) {
        float4 v = ((const float4*)rp)[tid + THREADS * j];
        float4 w; w.x = 1.f - v.x; w.y = 1.f - v.y; w.z = 1.f - v.z; w.w = 1.f - v.w;
        u[tid + THREADS * j] = w;
    }
    __syncthreads();

    float s_f = 0.f, q_f = 0.f;
    for (int rr = 0; rr < ROWS_PER_BLK; ++rr) {
        const int s = rblk * ROWS_PER_BLK + rr;
        const float4 rs = ((const float4*)rp)[s];
        #pragma unroll
        for (int j = 0; j < 8; ++j) {
            float4 w = u[tid + THREADS * j];
            float d0 = rs.x * w.x, d1 = rs.y * w.y, d2 = rs.z * w.z, d3 = rs.w * w.w;
            float dist = (d0*d0 + d1*d1) + (d2*d2 + d3*d3);
            s_f += dist;
            q_f += dist * dist;
        }
    }

    double sum   = wave_reduce_add_d((double)s_f);
    double sumsq = wave_reduce_add_d((double)q_f);
    __shared__ double red[8];
    const int wid = tid >> 6, lane = tid & 63;
    if (lane == 0) { red[wid*2] = sum; red[wid*2+1] = sumsq; }
    __syncthreads();
    if (tid == 0) {
        partials[bid*2+0] = red[0] + red[2] + red[4] + red[6];
        partials[bid*2+1] = red[1] + red[3] + red[5] + red[7];
    }
}

// Pass 2 (fused threshold + attention): 8 rows/block, wave-per-row.
// grid = (256 row-blocks, 4 batches). Each block:
//   - stages (1-r_t) in LDS once (shared by 8 rows)
//   - redundantly reduces its batch's 512 f64 partials (4KB, L2-hit) -> thr
//   - each wave owns 2 rows: butterfly row-sum, no block barriers after staging
__global__ __launch_bounds__(THREADS) void k_attn(const float* __restrict__ r,
                                                  const double* __restrict__ partials,
                                                  float* __restrict__ out) {
    const int rb = blockIdx.x;     // 0..255
    const int b  = blockIdx.y;     // 0..3
    const float* rp = r + (size_t)b * SEQ * 4;
    __shared__ float4 u[SEQ];      // 32KB
    __shared__ double red[8];
    const int tid = threadIdx.x, wid = tid >> 6, lane = tid & 63;

    #pragma unroll
    for (int j = 0; j < 8; ++j) {
        float4 v = ((const float4*)rp)[tid + THREADS * j];
        float4 w; w.x = 1.f - v.x; w.y = 1.f - v.y; w.z = 1.f - v.z; w.w = 1.f - v.w;
        u[tid + THREADS * j] = w;
    }

    // threshold reduce (fused into the staging barrier)
    double s = partials[(b*256 + tid)*2 + 0];
    double q = partials[(b*256 + tid)*2 + 1];
    s = wave_reduce_add_d(s);
    q = wave_reduce_add_d(q);
    if (lane == 0) { red[wid*2] = s; red[wid*2+1] = q; }
    __syncthreads();

    const double S0 = red[0] + red[2] + red[4] + red[6];
    const double S1 = red[1] + red[3] + red[5] + red[7];
    const double N = (double)SEQ * (double)SEQ;
    double mean = S0 / N;
    double var  = (S1 - S0 * S0 / N) / (N - 1.0);
    if (var < 0.0) var = 0.0;
    double sd = sqrt(var);
    if (sd < 1e-6) sd = 1e-6;
    const float T = (float)(mean + 1.25 * sd);

    // wave w handles rows rb*8 + 2w, rb*8 + 2w + 1
    #pragma unroll
    for (int rr = 0; rr < 2; ++rr) {
        const int srow = rb * ROWS_PER_BLK + wid * 2 + rr;
        const float4 rs = ((const float4*)rp)[srow];
        float att[32];
        float rowsum = 0.f;
        #pragma unroll
        for (int j = 0; j < 32; ++j) {
            float4 w = u[lane + 64 * j];
            float d0 = rs.x * w.x, d1 = rs.y * w.y, d2 = rs.z * w.z, d3 = rs.w * w.w;
            float s01  = d0*d0 + d1*d1;
            float dist = s01 + (d2*d2 + d3*d3);
            // cos(atan2(d1,d0)) == d0 * rsqrt(d0^2+d1^2); atan2(0,0)=0 -> cos=1
            float cosv = (s01 > 0.f) ? d0 * rsqrtf(s01) : 1.f;
            float bias = 0.5f * (1.f + cosv) * __expf(-dist);
            float a = (dist <= T) ? bias : 0.f;
            rowsum += a;
            att[j] = a;
        }
        const float inv = 1.0f / (wave_bcast_add_f(rowsum) + 1e-8f);
        float* orow = out + ((size_t)b * SEQ + srow) * SEQ;
        #pragma unroll
        for (int j = 0; j < 32; ++j) orow[lane + 64 * j] = att[j] * inv;
    }
}

extern "C" void kernel_launch(void* const* d_in, const int* in_sizes, int n_in,
                              void* d_out, int out_size, void* d_ws, size_t ws_size,
                              hipStream_t stream) {
    const float* r = (const float*)d_in[0];
    float* out = (float*)d_out;
    double* partials = (double*)d_ws;   // 1024*2 doubles = 16KB

    k_stats<<<dim3(K1_BLOCKS),   THREADS, 0, stream>>>(r, partials);
    k_attn <<<dim3(SEQ/ROWS_PER_BLK, NB), THREADS, 0, stream>>>(r, partials, out);
}

// Round 4
// 96.617 us; speedup vs baseline: 1.0336x; 1.0130x over previous
//
#include <hip/hip_runtime.h>
#include <math.h>

#define SEQ 2048
#define NB 4
#define THREADS 256
#define BPB 128             // blocks per batch (both kernels)
#define BLOCKS (NB * BPB)   // 512
#define ROWS 16             // rows per block

__device__ __forceinline__ float wave_bcast_add_f(float v) {
    #pragma unroll
    for (int o = 1; o < 64; o <<= 1) v += __shfl_xor(v, o, 64);
    return v;   // all lanes hold the sum
}
__device__ __forceinline__ double wave_reduce_add_d(double v) {
    #pragma unroll
    for (int o = 32; o > 0; o >>= 1) v += __shfl_down(v, o, 64);
    return v;   // lane 0 holds the sum
}

// Pass 1: per-block partial (sum, sumsq) of dist_sq over 16 rows.
// Per-thread accumulation in f32 (128 terms, rel err ~1e-6 -> threshold shift
// ~1e-5; border bias ~ exp(-T) ~ 1e-8 so flips are invisible), f64 across threads.
__global__ __launch_bounds__(THREADS) void k_stats(const float* __restrict__ r,
                                                   double* __restrict__ partials) {
    const int bid  = blockIdx.x;        // 0..511
    const int b    = bid >> 7;          // batch
    const int rblk = bid & (BPB - 1);
    const float* rp = r + (size_t)b * SEQ * 4;
    __shared__ float4 u[SEQ];           // (1 - r_t), 32KB
    const int tid = threadIdx.x;

    #pragma unroll
    for (int j = 0; j < 8; ++j) {
        float4 v = ((const float4*)rp)[tid + THREADS * j];
        float4 w; w.x = 1.f - v.x; w.y = 1.f - v.y; w.z = 1.f - v.z; w.w = 1.f - v.w;
        u[tid + THREADS * j] = w;
    }
    __syncthreads();

    float s_f = 0.f, q_f = 0.f;
    for (int rr = 0; rr < ROWS; ++rr) {
        const float4 rs = ((const float4*)rp)[rblk * ROWS + rr];
        #pragma unroll
        for (int j = 0; j < 8; ++j) {
            float4 w = u[tid + THREADS * j];
            float d0 = rs.x * w.x, d1 = rs.y * w.y, d2 = rs.z * w.z, d3 = rs.w * w.w;
            float dist = (d0*d0 + d1*d1) + (d2*d2 + d3*d3);
            s_f += dist;
            q_f += dist * dist;
        }
    }

    double sum   = wave_reduce_add_d((double)s_f);
    double sumsq = wave_reduce_add_d((double)q_f);
    __shared__ double red[8];
    const int wid = tid >> 6, lane = tid & 63;
    if (lane == 0) { red[wid*2] = sum; red[wid*2+1] = sumsq; }
    __syncthreads();
    if (tid == 0) {
        partials[bid*2+0] = red[0] + red[2] + red[4] + red[6];
        partials[bid*2+1] = red[1] + red[3] + red[5] + red[7];
    }
}

// Pass 2 (fused threshold + attention): 16 rows/block, 4 rows/wave.
// Block stages (1-r_t) once; redundantly reduces its batch's 128 f64 partials
// (2KB, L2-hit) during the staging barrier; then wave-per-row with butterfly
// row sums, zero block barriers after staging, nontemporal streaming stores.
__global__ __launch_bounds__(THREADS) void k_attn(const float* __restrict__ r,
                                                  const double* __restrict__ partials,
                                                  float* __restrict__ out) {
    const int bid = blockIdx.x;     // 0..511
    const int b   = bid >> 7;
    const int rblk = bid & (BPB - 1);
    const float* rp = r + (size_t)b * SEQ * 4;
    __shared__ float4 u[SEQ];       // 32KB
    __shared__ double red[8];
    const int tid = threadIdx.x, wid = tid >> 6, lane = tid & 63;

    #pragma unroll
    for (int j = 0; j < 8; ++j) {
        float4 v = ((const float4*)rp)[tid + THREADS * j];
        float4 w; w.x = 1.f - v.x; w.y = 1.f - v.y; w.z = 1.f - v.z; w.w = 1.f - v.w;
        u[tid + THREADS * j] = w;
    }

    // threshold reduce, hidden under the staging barrier
    double s = (tid < BPB) ? partials[(b*BPB + tid)*2 + 0] : 0.0;
    double q = (tid < BPB) ? partials[(b*BPB + tid)*2 + 1] : 0.0;
    s = wave_reduce_add_d(s);
    q = wave_reduce_add_d(q);
    if (lane == 0) { red[wid*2] = s; red[wid*2+1] = q; }
    __syncthreads();

    const double S0 = red[0] + red[2] + red[4] + red[6];
    const double S1 = red[1] + red[3] + red[5] + red[7];
    const double N = (double)SEQ * (double)SEQ;
    double mean = S0 / N;
    double var  = (S1 - S0 * S0 / N) / (N - 1.0);
    if (var < 0.0) var = 0.0;
    double sd = sqrt(var);
    if (sd < 1e-6) sd = 1e-6;
    const float T = (float)(mean + 1.25 * sd);

    // wave wid handles rows rblk*16 + wid*4 .. +3
    #pragma unroll
    for (int rr = 0; rr < 4; ++rr) {
        const int srow = rblk * ROWS + wid * 4 + rr;
        const float4 rs = ((const float4*)rp)[srow];
        float att[32];
        float rowsum = 0.f;
        #pragma unroll
        for (int j = 0; j < 32; ++j) {
            float4 w = u[lane + 64 * j];
            float d0 = rs.x * w.x, d1 = rs.y * w.y, d2 = rs.z * w.z, d3 = rs.w * w.w;
            float s01  = d0*d0 + d1*d1;
            float dist = s01 + (d2*d2 + d3*d3);
            // cos(atan2(d1,d0)) == d0 * rsqrt(d0^2+d1^2); atan2(0,0)=0 -> cos=1
            float cosv = (s01 > 0.f) ? d0 * rsqrtf(s01) : 1.f;
            float bias = 0.5f * (1.f + cosv) * __expf(-dist);
            float a = (dist <= T) ? bias : 0.f;
            rowsum += a;
            att[j] = a;
        }
        const float inv = 1.0f / (wave_bcast_add_f(rowsum) + 1e-8f);
        float* orow = out + ((size_t)b * SEQ + srow) * SEQ;
        #pragma unroll
        for (int j = 0; j < 32; ++j)
            __builtin_nontemporal_store(att[j] * inv, orow + lane + 64 * j);
    }
}

extern "C" void kernel_launch(void* const* d_in, const int* in_sizes, int n_in,
                              void* d_out, int out_size, void* d_ws, size_t ws_size,
                              hipStream_t stream) {
    const float* r = (const float*)d_in[0];
    float* out = (float*)d_out;
    double* partials = (double*)d_ws;   // 512*2 doubles = 8KB

    k_stats<<<dim3(BLOCKS), THREADS, 0, stream>>>(r, partials);
    k_attn <<<dim3(BLOCKS), THREADS, 0, stream>>>(r, partials, out);
}